// Round 12
// baseline (150561.316 us; speedup 1.0000x reference)
//
#include <hip/hip_runtime.h>
#include <hip/hip_cooperative_groups.h>

namespace cg = cooperative_groups;

constexpr int NB   = 64;
constexpr int NS   = 256;
constexpr int NT   = 500;
constexpr int NMEL = 80;
constexpr int NE   = 512;
constexpr int NP   = 256;
constexpr int NA   = 1024;
constexpr int ND   = 1024;
constexpr int NAD  = 128;
constexpr int ZC   = 4096;
constexpr int KA   = 1792;
constexpr int KD   = 2560;
constexpr int G    = 512;

constexpr int SMN  = 5280;

// ---- MODE2 layout (fallback) ----
constexpr long M2_W2   = 0;
constexpr long M2_ZAP  = M2_W2 + 62 * NAD;
constexpr long M2_ZDP  = M2_ZAP + 2 * NB * ZC;
constexpr long M2_HA   = M2_ZDP + 2 * NB * ZC;
constexpr long M2_CA   = M2_HA + NB * NA;
constexpr long M2_HD   = M2_CA + NB * NA;
constexpr long M2_CD   = M2_HD + NB * ND;
constexpr long M2_CTX  = M2_CD + NB * ND;
constexpr long M2_WGL  = M2_CTX + 2 * NB * NE;
constexpr long M2_WCU  = M2_WGL + NB * NS;
constexpr long M2_PM1  = M2_WCU + NB * NS;
constexpr long M2_ZCNT = M2_PM1 - M2_HA;
constexpr long M2_BAR  = M2_PM1 + NB * NP;
constexpr long M2_FEND = M2_BAR + 1024;
constexpr long M2_WAT   = 0;
constexpr long M2_WDT   = M2_WAT + (long)ZC * KA;
constexpr long M2_X16A  = M2_WDT + (long)ZC * KD;
constexpr long M2_X16D  = M2_X16A + (long)NB * KA;
constexpr long M2_K16   = M2_X16D + (long)NB * KD;
constexpr long M2_FL16  = M2_K16 + (long)NB * NAD * NS;
constexpr long M2_MEM16 = M2_FL16 + (long)NB * NAD * NS;
constexpr long M2_UEND_NM = M2_MEM16;
constexpr long M2_UEND    = M2_MEM16 + (long)NB * NS * NE;
constexpr long M2_BYTES_NM = M2_FEND * 4 + M2_UEND_NM * 2;
constexpr long M2_BYTES    = M2_FEND * 4 + M2_UEND * 2;

// ---- MODE7 layout: LDS-resident weights, natural mem16, 3-phase ----
constexpr int G3 = 256, T3 = 512;
constexpr long M3_W2   = 0;                         // [62][128]
constexpr long M3_ZA   = M3_W2 + 62 * NAD;          // [64][4096]
constexpr long M3_ZD   = M3_ZA + NB * ZC;           // [64][4096]
constexpr long M3_CTX  = M3_ZD + NB * ZC;           // [2][64][512]
constexpr long M3_WGL  = M3_CTX + 2 * NB * NE;      // [64][256]
constexpr long M3_WCU  = M3_WGL + NB * NS;
constexpr long M3_PM1  = M3_WCU + NB * NS;          // [64][256]
constexpr long M3_BAR  = M3_PM1 + NB * NP;          // 1024 uints
constexpr long M3_FEND = M3_BAR + 1024;
// ushorts at (ushort*)(ws + M3_FEND)
constexpr long M3_WAT  = 0;                          // [256][56][512]
constexpr long M3_WDT  = M3_WAT + (long)ZC * KA;     // [256][80][512]
constexpr long M3_X16A = M3_WDT + (long)ZC * KD;     // [64][1792]
constexpr long M3_X16D = M3_X16A + (long)NB * KA;    // [64][2560]
constexpr long M3_K16  = M3_X16D + (long)NB * KD;    // [64][128 ad][256 s]
constexpr long M3_FL16 = M3_K16 + (long)NB * NAD * NS;
constexpr long M3_WQ16 = M3_FL16 + (long)NB * NAD * NS; // [1024 k][128 ad]
constexpr long M3_MEM16 = M3_WQ16 + (long)NA * NAD;  // [64][256 s][512 e]
constexpr long M3_UEND = M3_MEM16 + (long)NB * NS * NE;
constexpr long M3_BYTES = M3_FEND * 4 + M3_UEND * 2; // ~64.2 MB
constexpr int  DYN_LDS  = 159744;                    // 57344 + 81920 + 20480

constexpr long MEL_BASE   = 0;
constexpr long STOP_BASE  = (long)NB * NT * NMEL;
constexpr long ALIGN_BASE = STOP_BASE + (long)NB * NT;

typedef __attribute__((ext_vector_type(8))) short bf16x8;
typedef __attribute__((ext_vector_type(4))) float f32x4;

struct Params {
  const float *memory, *mel, *pw1, *pw2, *awx, *awh, *ab, *wq, *wm,
              *lconv, *wloc, *vatt, *dwx, *dwh, *db, *projw, *projb, *gatew, *gateb;
  float *out, *ws;
};

__device__ __forceinline__ float sigm(float x) { return 1.f / (1.f + __expf(-x)); }
__device__ __forceinline__ float tanh_t(float x) {
  x = fminf(fmaxf(x, -15.f), 15.f);
  const float a = __expf(2.f * x);
  return (a - 1.f) / (a + 1.f);
}
__device__ __forceinline__ unsigned short f2bf(float x) {
  union { float f; unsigned u; } c; c.f = x;
  const unsigned r = c.u + 0x7FFFu + ((c.u >> 16) & 1u);
  return (unsigned short)(r >> 16);
}
__device__ __forceinline__ float bf2f(unsigned short v) {
  union { unsigned u; float f; } c; c.u = (unsigned)v << 16;
  return c.f;
}

// ---- fenced grid barrier (512-grid fallback), 32-block leaves ----
__device__ __forceinline__ void gbar(unsigned* bar, int wg, int tid) {
  __syncthreads();
  if (tid == 0) {
    unsigned* gen  = bar;
    unsigned* root = bar + 32;
    unsigned* leaf = bar + 64 + (wg >> 5) * 32;
    const unsigned g = __hip_atomic_load(gen, __ATOMIC_RELAXED, __HIP_MEMORY_SCOPE_AGENT);
    __threadfence();
    const unsigned lo = __hip_atomic_fetch_add(leaf, 1u, __ATOMIC_ACQ_REL,
                                               __HIP_MEMORY_SCOPE_AGENT);
    if (lo == 31) {
      __hip_atomic_store(leaf, 0u, __ATOMIC_RELAXED, __HIP_MEMORY_SCOPE_AGENT);
      const unsigned ro = __hip_atomic_fetch_add(root, 1u, __ATOMIC_ACQ_REL,
                                                 __HIP_MEMORY_SCOPE_AGENT);
      if (ro == 15) {
        __hip_atomic_store(root, 0u, __ATOMIC_RELAXED, __HIP_MEMORY_SCOPE_AGENT);
        __hip_atomic_fetch_add(gen, 1u, __ATOMIC_ACQ_REL, __HIP_MEMORY_SCOPE_AGENT);
      }
    }
    while (__hip_atomic_load(gen, __ATOMIC_RELAXED, __HIP_MEMORY_SCOPE_AGENT) == g)
      __builtin_amdgcn_s_sleep(16);
    __threadfence();
  }
  __syncthreads();
}

// ---- fenced grid barrier (MODE7, 256-grid), 16 leaves x 16 blocks ----
__device__ __forceinline__ void gbar3(unsigned* bar, int wg, int tid) {
  __syncthreads();
  if (tid == 0) {
    unsigned* gen  = bar;
    unsigned* root = bar + 32;
    unsigned* leaf = bar + 64 + (wg >> 4) * 32;
    const unsigned g = __hip_atomic_load(gen, __ATOMIC_RELAXED, __HIP_MEMORY_SCOPE_AGENT);
    __threadfence();
    const unsigned lo = __hip_atomic_fetch_add(leaf, 1u, __ATOMIC_ACQ_REL,
                                               __HIP_MEMORY_SCOPE_AGENT);
    if (lo == 15) {
      __hip_atomic_store(leaf, 0u, __ATOMIC_RELAXED, __HIP_MEMORY_SCOPE_AGENT);
      const unsigned ro = __hip_atomic_fetch_add(root, 1u, __ATOMIC_ACQ_REL,
                                                 __HIP_MEMORY_SCOPE_AGENT);
      if (ro == 15) {
        __hip_atomic_store(root, 0u, __ATOMIC_RELAXED, __HIP_MEMORY_SCOPE_AGENT);
        __hip_atomic_fetch_add(gen, 1u, __ATOMIC_ACQ_REL, __HIP_MEMORY_SCOPE_AGENT);
      }
    }
    while (__hip_atomic_load(gen, __ATOMIC_RELAXED, __HIP_MEMORY_SCOPE_AGENT) == g)
      __builtin_amdgcn_s_sleep(8);
    __threadfence();
  }
  __syncthreads();
}

// prenet stage 1 (call with tid<256)
__device__ void do_s1(const Params& p, float* pm1, int tnext, int wl, int tid) {
  const int col = tid;
  for (int i = 0; i < 8; ++i) {
    const int b = wl * 8 + i;
    const float* mrow = p.mel + ((size_t)b * NT + tnext) * NMEL;
    float acc = 0.f;
    for (int k = 0; k < NMEL; ++k) acc += mrow[k] * p.pw1[k * NP + col];
    pm1[b * NP + col] = fmaxf(acc, 0.f);
  }
}

// prenet stage 2 (call with tid<256)
template<int MODE>
__device__ void do_s2(const Params& p, const float* pm1, float* pdst,
                      unsigned short* xA, int wl, int tid) {
  const int col = tid;
  for (int i = 0; i < 4; ++i) {
    const int b = wl * 4 + i;
    const float* pr = pm1 + b * NP;
    float acc = 0.f;
    for (int k = 0; k < NP; ++k) acc += pr[k] * p.pw2[k * NP + col];
    const float v = fmaxf(acc, 0.f);
    if constexpr (MODE >= 2) xA[(size_t)b * KA + col] = f2bf(v);
    else                     pdst[b * NP + col] = v;
  }
}

// ======================= MODE7 =======================
__device__ void do_fl3(const Params& p, float* scr, unsigned short* u16, int wg, int tid) {
  float* ws = p.ws;
  float* chunk = scr;              // 3968 f
  float* wp = scr + 3968;          // [2][2][288]
  const int hf = tid >> 8, ts = tid & 255;
  const int b = (wg - 144) * 2 + hf;
  float* wp0 = wp + hf * 576;
  float* wp1 = wp0 + 288;
  for (int i = ts; i < 288; i += 256) { wp0[i] = 0.f; wp1[i] = 0.f; }
  __syncthreads();
  wp0[15 + ts] = ws[M3_WGL + b * NS + ts];
  wp1[15 + ts] = ws[M3_WCU + b * NS + ts];
  __syncthreads();
  float x0[31], x1[31];
#pragma unroll
  for (int k = 0; k < 31; ++k) { x0[k] = wp0[ts + k]; x1[k] = wp1[ts + k]; }
  const unsigned short* kb16 = u16 + M3_K16 + (size_t)(b * NAD) * NS + ts;
  unsigned short* fb16 = u16 + M3_FL16 + (size_t)(b * NAD) * NS + ts;
  const float* W2g = ws + M3_W2;
  for (int ch = 0; ch < 2; ++ch) {
    for (int i = tid; i < 62 * 64; i += T3) {
      const int k2 = i >> 6, adl = i & 63;
      chunk[i] = W2g[k2 * NAD + ch * 64 + adl];
    }
    __syncthreads();
    for (int adl = 0; adl < 64; ++adl) {
      const int ad = ch * 64 + adl;
      float acc = bf2f(kb16[(size_t)ad * NS]);
#pragma unroll
      for (int k = 0; k < 31; ++k)
        acc = fmaf(x0[k], chunk[(2 * k) * 64 + adl],
              fmaf(x1[k], chunk[(2 * k + 1) * 64 + adl], acc));
      fb16[(size_t)ad * NS] = f2bf(acc);
    }
    __syncthreads();
  }
}

// attn (P2a): LSTM-A + query + energies + softmax (NO ctx; ctx moved to P2b)
__device__ void attn3(const Params& p, float* scr, unsigned short* u16,
                      int b, int tid, int t, float& c0, float& c1) {
  if (t >= NT) return;
  float* ws = p.ws;
  float* h_sh = scr;
  float* red  = scr + 1024;
  float* q_sh = scr + 1536;
  unsigned short* xA = u16 + M3_X16A + (size_t)b * KA;
  unsigned short* xD = u16 + M3_X16D + (size_t)b * KD;
  const float* za = ws + M3_ZA + (size_t)b * ZC;
#pragma unroll
  for (int j = 0; j < 2; ++j) {
    const int g = tid + j * 512;
    const float zi = p.ab[g] + za[g];
    const float zf = p.ab[1024 + g] + za[1024 + g];
    const float zg = p.ab[2048 + g] + za[2048 + g];
    const float zo = p.ab[3072 + g] + za[3072 + g];
    float& cc = j ? c1 : c0;
    const float iv = sigm(zi), fv = sigm(zf), gv = tanh_t(zg), ov = sigm(zo);
    const float cn = fv * cc + iv * gv;
    const float h2 = ov * tanh_t(cn);
    cc = cn;
    h_sh[g] = h2;
    xA[768 + g] = f2bf(h2);
    xD[g]       = f2bf(h2);
  }
  __syncthreads();
  // query: ad 128 x 4-way ksplit (bf16 wq [k][ad], lane-coalesced)
  {
    const int ad = tid & 127, kh = tid >> 7;
    const unsigned short* wqp = u16 + M3_WQ16 + ad;
    float acc = 0.f;
#pragma unroll 16
    for (int k = kh * 256; k < kh * 256 + 256; ++k) acc += h_sh[k] * bf2f(wqp[(size_t)k * NAD]);
    red[tid] = acc;
  }
  __syncthreads();
  if (tid < 128) q_sh[tid] = red[tid] + red[tid + 128] + red[tid + 256] + red[tid + 384];
  __syncthreads();
  // energies: s 256 x 2-way ad-split (FL16[b][ad][s], lane-coalesced)
  float evp = 0.f;
  {
    const int s = tid & 255, hf = tid >> 8;
    const unsigned short* flp = u16 + M3_FL16 + (size_t)(b * NAD + hf * 64) * NS + s;
    const float* qs = q_sh + hf * 64;
    const float* va = p.vatt + hf * 64;
#pragma unroll 8
    for (int ad = 0; ad < 64; ++ad)
      evp += tanh_t(qs[ad] + bf2f(flp[(size_t)ad * NS])) * va[ad];
  }
  red[tid] = evp;
  __syncthreads();
  float evs = 0.f;
  if (tid < 256) evs = red[tid] + red[tid + 256];
  __syncthreads();
  if (tid < 256) red[tid] = evs;
  __syncthreads();
  for (int off = 128; off > 0; off >>= 1) {
    if (tid < off) red[tid] = fmaxf(red[tid], red[tid + off]);
    __syncthreads();
  }
  const float mx = red[0];
  __syncthreads();
  const float ex = (tid < 256) ? __expf(evs - mx) : 0.f;
  red[tid] = ex;
  __syncthreads();
  for (int off = 128; off > 0; off >>= 1) {
    if (tid < off) red[tid] += red[tid + off];
    __syncthreads();
  }
  const float sden = red[0];
  if (tid < 256) {
    const float wv = ex / sden;
    ws[M3_WGL + b * NS + tid] = wv;
    ws[M3_WCU + b * NS + tid] += wv;
    p.out[ALIGN_BASE + (size_t)b * NT * NS + (size_t)t * NS + tid] = wv;
  }
}

// ctx (P2b): spread over all 256 blocks; block = (b, 128-e chunk)
__device__ void do_ctx(const Params& p, float* scr, unsigned short* u16,
                       int wg, int tid, int t) {
  if (t >= NT) return;
  float* ws = p.ws;
  const int b = wg >> 2, e0 = (wg & 3) * 128;
  float* w_sh = scr;           // 256
  float* psum = scr + 256;     // 512
  for (int i = tid; i < NS; i += T3) w_sh[i] = ws[M3_WGL + b * NS + i];
  __syncthreads();
  const int sq = tid >> 7, el = tid & 127;
  const unsigned short* mb = u16 + M3_MEM16
      + ((size_t)b * NS + sq * 64) * NE + e0 + el;
  float a = 0.f;
#pragma unroll 16
  for (int s = 0; s < 64; ++s)
    a += w_sh[sq * 64 + s] * bf2f(mb[(size_t)s * NE]);
  psum[tid] = a;
  __syncthreads();
  if (tid < 128) {
    const float v = psum[el] + psum[128 + el] + psum[256 + el] + psum[384 + el];
    const int e = e0 + el;
    ws[M3_CTX + (t & 1) * (NB * NE) + b * NE + e] = v;
    unsigned short* xA = u16 + M3_X16A + (size_t)b * KA;
    unsigned short* xD = u16 + M3_X16D + (size_t)b * KD;
    const unsigned short bv = f2bf(v);
    xA[256 + e]  = bv;
    xD[1024 + e] = bv;
  }
}

__device__ void dec3(const Params& p, float* scr, unsigned short* u16,
                     int b, int tid, int t, float& c0, float& c1) {
  if (t < 1) return;
  const int tm1 = t - 1;
  float* ws = p.ws;
  float* h_sh = scr;
  float* red  = scr + 1024;
  unsigned short* xD = u16 + M3_X16D + (size_t)b * KD;
  const float* zd = ws + M3_ZD + (size_t)b * ZC;
#pragma unroll
  for (int j = 0; j < 2; ++j) {
    const int g = tid + j * 512;
    const float zi = p.db[g] + zd[g];
    const float zf = p.db[1024 + g] + zd[1024 + g];
    const float zg = p.db[2048 + g] + zd[2048 + g];
    const float zo = p.db[3072 + g] + zd[3072 + g];
    float& cc = j ? c1 : c0;
    const float iv = sigm(zi), fv = sigm(zf), gv = tanh_t(zg), ov = sigm(zo);
    const float cn = fv * cc + iv * gv;
    const float h2 = ov * tanh_t(cn);
    cc = cn;
    h_sh[g] = h2;
    xD[1536 + g] = f2bf(h2);
  }
  __syncthreads();
  const float* ctxf = ws + M3_CTX + (tm1 & 1) * (NB * NE) + b * NE;
  // stop gate
  red[tid] = h_sh[tid] * p.gatew[tid] + h_sh[tid + 512] * p.gatew[tid + 512]
           + ctxf[tid] * p.gatew[tid + 1024];
  __syncthreads();
  for (int off = 256; off > 0; off >>= 1) {
    if (tid < off) red[tid] += red[tid + off];
    __syncthreads();
  }
  if (tid == 0) p.out[STOP_BASE + (size_t)b * NT + tm1] = sigm(red[0] + p.gateb[0]);
  __syncthreads();
  // mel projection: 80 m x 6-way ksplit (projw [k][m], lane-coalesced)
  if (tid < 480) {
    const int m = tid % 80, kh = tid / 80;
    float acc = 0.f;
#pragma unroll 8
    for (int k = kh * 256; k < kh * 256 + 256; ++k) {
      const float v = (k < 1024) ? h_sh[k] : ctxf[k - 1024];
      acc += v * p.projw[(size_t)k * 80 + m];
    }
    red[kh * 80 + m] = acc;
  }
  __syncthreads();
  if (tid < 80) {
    float mval = p.projb[tid];
#pragma unroll
    for (int kh = 0; kh < 6; ++kh) mval += red[kh * 80 + tid];
    p.out[MEL_BASE + (size_t)b * NT * NMEL + (size_t)tm1 * NMEL + tid] = mval;
  }
}

__global__ __launch_bounds__(512, 1) void taco3(Params p) {
  cg::grid_group grid = cg::this_grid();
  const int wg = blockIdx.x, tid = threadIdx.x;
  extern __shared__ char dynsm[];
  unsigned short* wA_l = (unsigned short*)dynsm;              // 57344 B
  unsigned short* wD_l = (unsigned short*)(dynsm + 57344);    // 81920 B
  float* scr = (float*)(dynsm + 139264);                      // 20480 B scratch
  float* ws = p.ws;
  unsigned short* u16 = (unsigned short*)(ws + M3_FEND);

  // ---------------- pre-phase A ----------------
  {
    const long gid = (long)wg * T3 + tid, gstr = (long)G3 * T3;
    for (long i = gid; i < 98304; i += gstr) ws[M3_CTX + i] = 0.f;  // ctx+w+wcum
    if (wg == 0) for (int i = tid; i < 1024; i += T3) ((unsigned*)(ws + M3_BAR))[i] = 0;
    for (long i = gid; i < 62 * NAD; i += gstr) {
      const int k2 = (int)(i >> 7), ad = (int)(i & 127);
      float a = 0.f;
      for (int f = 0; f < 32; ++f) a += p.lconv[k2 * 32 + f] * p.wloc[f * NAD + ad];
      ws[M3_W2 + i] = a;
    }
    for (long i = gid; i < (long)NB * KA + (long)NB * KD; i += gstr) u16[M3_X16A + i] = 0;
    for (long i = gid; i < (long)NA * NAD; i += gstr) u16[M3_WQ16 + i] = f2bf(p.wq[i]);
    for (long i = gid; i < (long)NB * NS * NE; i += gstr)
      u16[M3_MEM16 + i] = f2bf(p.memory[i]);
    // keysT bf16 [b][ad][s]: 4 WGs per b, 64-s chunk, 16 ad-groups of 8
    {
      const int b = wg >> 2, s0 = (wg & 3) * 64;
      const int sl = tid & 31, adg = tid >> 5;  // 0..15
      const float* wmb = p.wm + adg * 8;
      for (int so = 0; so < 64; so += 32) {
        const float* mrow = p.memory + (size_t)(b * NS + s0 + so + sl) * NE;
        float acc[8];
#pragma unroll
        for (int j = 0; j < 8; ++j) acc[j] = 0.f;
        for (int k = 0; k < NE; ++k) {
          const float mv = mrow[k];
          const float* wr = wmb + (size_t)k * NAD;
#pragma unroll
          for (int j = 0; j < 8; ++j) acc[j] += mv * wr[j];
        }
#pragma unroll
        for (int j = 0; j < 8; ++j)
          u16[M3_K16 + (size_t)(b * NAD + adg * 8 + j) * NS + s0 + so + sl] = f2bf(acc[j]);
      }
    }
    // pack bf16 weight fragments -> global WAT/WDT (tiles of 32k x 64n)
    for (int tile = wg; tile < 3584 + 5120; tile += G3) {
      const bool iA = tile < 3584;
      const int tt = iA ? tile : tile - 3584;
      const int NKB = iA ? 56 : 80;
      const int nt4 = tt / NKB, kb = tt % NKB;
      const int kx = iA ? 768 : 1536;
      float4 v0{}, v1{};
      if (tid < 256) {
        const int r = tid >> 3, cgp = (tid & 7) * 8;
        const int k = kb * 32 + r;
        const float* src = iA
            ? (k < kx ? p.awx + (size_t)k * ZC : p.awh + (size_t)(k - kx) * ZC)
            : (k < kx ? p.dwx + (size_t)k * ZC : p.dwh + (size_t)(k - kx) * ZC);
        const float* sp = src + nt4 * 64 + cgp;
        v0 = *(const float4*)sp;
        v1 = *(const float4*)(sp + 4);
      }
      __syncthreads();
      if (tid < 256) {
        const int r = tid >> 3, cgp = (tid & 7) * 8;
        *(float4*)(scr + r * 64 + cgp)     = v0;
        *(float4*)(scr + r * 64 + cgp + 4) = v1;
      }
      __syncthreads();
      if (tid < 256) {
        const int blk = tid >> 6, l = tid & 63;
        const int n16 = nt4 * 4 + blk;
        bf16x8 pk;
#pragma unroll
        for (int j = 0; j < 8; ++j)
          pk[j] = (short)f2bf(scr[((l >> 4) * 8 + j) * 64 + blk * 16 + (l & 15)]);
        unsigned short* dst = u16 + (iA ? M3_WAT : M3_WDT)
                            + ((size_t)(n16 * NKB + kb)) * 512 + l * 8;
        *(bf16x8*)dst = pk;
      }
      __syncthreads();
    }
    if (wg >= 176 && wg < 184 && tid < 256) do_s1(p, ws + M3_PM1, 0, wg - 176, tid);
  }
  grid.sync();
  // ---------------- pre-phase B: LDS-stage weights; s2(0) ----------------
  {
    const float4* srcA = (const float4*)(u16 + M3_WAT + (size_t)wg * 56 * 512);
    float4* dA = (float4*)wA_l;
    for (int i = tid; i < 3584; i += T3) dA[i] = srcA[i];
    const float4* srcD = (const float4*)(u16 + M3_WDT + (size_t)wg * 80 * 512);
    float4* dD = (float4*)wD_l;
    for (int i = tid; i < 5120; i += T3) dD[i] = srcD[i];
    if (wg >= 128 && wg < 144 && tid < 256)
      do_s2<3>(p, ws + M3_PM1, nullptr, u16 + M3_X16A, wg - 128, tid);
  }
  grid.sync();

  float c0 = 0.f, c1 = 0.f;   // recurrent cell state in registers (attn/dec roles)
  unsigned* bar = (unsigned*)(ws + M3_BAR);
  for (int t = 0; t <= NT; ++t) {
    // ========== phase 1: GEMMs + fl + s1 ==========
    {
      const int wid = tid >> 6, l = tid & 63;
      if (wid < 4) {
        if (t < NT) {  // A-GEMM
          const unsigned short* xb = u16 + M3_X16A
              + (size_t)(wid * 16 + (l & 15)) * KA + (l >> 4) * 8;
          f32x4 acc{0.f, 0.f, 0.f, 0.f};
#pragma unroll 8
          for (int ks = 0; ks < 56; ++ks) {
            const bf16x8 bfr = *(const bf16x8*)(wA_l + ks * 512 + l * 8);
            const bf16x8 a   = *(const bf16x8*)(xb + ks * 32);
            acc = __builtin_amdgcn_mfma_f32_16x16x32_bf16(a, bfr, acc, 0, 0, 0);
          }
          const int ncol = wg * 16 + (l & 15), rb = (l >> 4) * 4;
          float* z = ws + M3_ZA;
#pragma unroll
          for (int r = 0; r < 4; ++r) z[(size_t)(wid * 16 + rb + r) * ZC + ncol] = acc[r];
        }
      } else {
        if (t >= 1) {  // D-GEMM
          const int mb = wid - 4;
          const unsigned short* xb = u16 + M3_X16D
              + (size_t)(mb * 16 + (l & 15)) * KD + (l >> 4) * 8;
          f32x4 acc{0.f, 0.f, 0.f, 0.f};
#pragma unroll 8
          for (int ks = 0; ks < 80; ++ks) {
            const bf16x8 bfr = *(const bf16x8*)(wD_l + ks * 512 + l * 8);
            const bf16x8 a   = *(const bf16x8*)(xb + ks * 32);
            acc = __builtin_amdgcn_mfma_f32_16x16x32_bf16(a, bfr, acc, 0, 0, 0);
          }
          const int ncol = wg * 16 + (l & 15), rb = (l >> 4) * 4;
          float* z = ws + M3_ZD;
#pragma unroll
          for (int r = 0; r < 4; ++r) z[(size_t)(mb * 16 + rb + r) * ZC + ncol] = acc[r];
        }
      }
      if (wg >= 144 && wg < 176) {
        if (t < NT) do_fl3(p, scr, u16, wg, tid);
      } else if (wg >= 176 && wg < 184) {
        if (t + 1 < NT && tid < 256) do_s1(p, ws + M3_PM1, t + 1, wg - 176, tid);
      }
    }
    gbar3(bar, wg, tid);
    // ========== phase 2a: attn softmax / dec / s2 ==========
    if (wg < 64)       attn3(p, scr, u16, wg, tid, t, c0, c1);
    else if (wg < 128) dec3(p, scr, u16, wg - 64, tid, t, c0, c1);
    else if (wg < 144) {
      if (t + 1 < NT && tid < 256)
        do_s2<3>(p, ws + M3_PM1, nullptr, u16 + M3_X16A, wg - 128, tid);
    }
    gbar3(bar, wg, tid);
    // ========== phase 2b: ctx spread over all blocks ==========
    do_ctx(p, scr, u16, wg, tid, t);
    gbar3(bar, wg, tid);
  }
}

// ======================= MODE2 (fallback, r7-proven) =======================
template<bool USEMEM>
__device__ void pre_a2(const Params& p, float* sm, int wg, int tid) {
  float* ws = p.ws;
  unsigned short* u16 = (unsigned short*)(ws + M2_FEND);
  const long gid = wg * 256 + tid;
  const long gstr = (long)G * 256;
  for (long i = gid; i < M2_ZCNT; i += gstr) (ws + M2_HA)[i] = 0.f;
  if (wg == 0) for (int i = tid; i < 1024; i += 256) ((unsigned*)(ws + M2_BAR))[i] = 0;
  for (long i = gid; i < 62 * NAD; i += gstr) {
    const int k2 = (int)(i >> 7), ad = (int)(i & 127);
    float acc = 0.f;
    for (int f = 0; f < 32; ++f) acc += p.lconv[k2 * 32 + f] * p.wloc[f * NAD + ad];
    ws[M2_W2 + i] = acc;
  }
  {
    const int b = wg >> 3, s0 = (wg & 7) * 32;
    const int sl = tid & 31, adg = tid >> 5;
    const float* mrow = p.memory + (size_t)(b * NS + s0 + sl) * NE;
    const float* wmb  = p.wm + adg * 16;
    float acc[16];
#pragma unroll
    for (int j = 0; j < 16; ++j) acc[j] = 0.f;
    for (int k = 0; k < NE; ++k) {
      const float mv = mrow[k];
      const float* wr = wmb + (size_t)k * NAD;
#pragma unroll
      for (int j = 0; j < 16; ++j) acc[j] += mv * wr[j];
    }
#pragma unroll
    for (int j = 0; j < 16; ++j)
      u16[M2_K16 + (size_t)(b * NAD + adg * 16 + j) * NS + s0 + sl] = f2bf(acc[j]);
  }
  for (long i = gid; i < (long)NB * KA + (long)NB * KD; i += gstr)
    u16[M2_X16A + i] = 0;
  if constexpr (USEMEM) {
    for (long i = gid; i < (long)NB * NS * NE; i += gstr)
      u16[M2_MEM16 + i] = f2bf(p.memory[i]);
  }
  for (int tile = wg; tile < 3584 + 5120; tile += G) {
    const bool iA = tile < 3584;
    const int tt = iA ? tile : tile - 3584;
    const int NKB = iA ? 56 : 80;
    const int nt4 = tt / NKB, kb = tt % NKB;
    const int kx = iA ? 768 : 1536;
    const int r = tid >> 3, cgp = (tid & 7) * 8;
    const int k = kb * 32 + r;
    const float* src = iA
        ? (k < kx ? p.awx + (size_t)k * ZC : p.awh + (size_t)(k - kx) * ZC)
        : (k < kx ? p.dwx + (size_t)k * ZC : p.dwh + (size_t)(k - kx) * ZC);
    const float* sp = src + nt4 * 64 + cgp;
    const float4 v0 = *(const float4*)sp;
    const float4 v1 = *(const float4*)(sp + 4);
    __syncthreads();
    *(float4*)(sm + r * 64 + cgp)     = v0;
    *(float4*)(sm + r * 64 + cgp + 4) = v1;
    __syncthreads();
    const int blk = tid >> 6, l = tid & 63;
    const int n16 = nt4 * 4 + blk;
    bf16x8 pk;
#pragma unroll
    for (int j = 0; j < 8; ++j)
      pk[j] = (short)f2bf(sm[((l >> 4) * 8 + j) * 64 + blk * 16 + (l & 15)]);
    unsigned short* dst = u16 + (iA ? M2_WAT : M2_WDT)
                        + ((size_t)(n16 * NKB + kb)) * 512 + l * 8;
    *(bf16x8*)dst = pk;
  }
  if (wg >= 320 && wg < 328) do_s1(p, ws + M2_PM1, 0, wg - 320, tid);
}

__device__ void do_fl2(const Params& p, float* sm, int b, int tid) {
  float* ws = p.ws;
  unsigned short* u16 = (unsigned short*)(ws + M2_FEND);
  float* chunk = sm;
  float* wp0 = sm + 4000;
  float* wp1 = sm + 4320;
  for (int i = tid; i < 288; i += 256) { wp0[i] = 0.f; wp1[i] = 0.f; }
  __syncthreads();
  wp0[15 + tid] = ws[M2_WGL + b * NS + tid];
  wp1[15 + tid] = ws[M2_WCU + b * NS + tid];
  __syncthreads();
  float x0[31], x1[31];
#pragma unroll
  for (int k = 0; k < 31; ++k) { x0[k] = wp0[tid + k]; x1[k] = wp1[tid + k]; }
  const unsigned short* kb16 = u16 + M2_K16 + (size_t)(b * NAD) * NS + tid;
  unsigned short* fb16 = u16 + M2_FL16 + (size_t)(b * NAD) * NS + tid;
  const float* W2g = ws + M2_W2;
  for (int ch = 0; ch < 2; ++ch) {
    for (int i = tid; i < 62 * 64; i += 256) {
      const int k2 = i >> 6, adl = i & 63;
      chunk[i] = W2g[k2 * NAD + ch * 64 + adl];
    }
    __syncthreads();
    for (int adl = 0; adl < 64; ++adl) {
      const int ad = ch * 64 + adl;
      float acc = bf2f(kb16[(size_t)ad * NS]);
#pragma unroll
      for (int k = 0; k < 31; ++k)
        acc = fmaf(x0[k], chunk[(2 * k) * 64 + adl],
              fmaf(x1[k], chunk[(2 * k + 1) * 64 + adl], acc));
      fb16[(size_t)ad * NS] = f2bf(acc);
    }
    __syncthreads();
  }
}

__device__ void phase1_2(const Params& p, float* sm, int wg, int tid, int t) {
  float* ws = p.ws;
  unsigned short* u16 = (unsigned short*)(ws + M2_FEND);
  if (wg < 256) {
    const bool isA = wg < 128;
    if ((isA && t < NT) || (!isA && t >= 1)) {
      const int g   = isA ? wg : wg - 128;
      const int kc  = g & 1, nb4 = g >> 1;
      const int NKB = isA ? 56 : 80;
      const int nks = isA ? 28 : 40;
      const int kb0 = kc * nks;
      const int Kp  = isA ? KA : KD;
      const unsigned short* wT  = u16 + (isA ? M2_WAT : M2_WDT);
      const unsigned short* x16 = u16 + (isA ? M2_X16A : M2_X16D);
      float* zout = ws + (isA ? M2_ZAP : M2_ZDP) + (size_t)kc * NB * ZC;
      const int l = tid & 63;
      const int n16 = nb4 * 4 + (tid >> 6);
      const unsigned short* wb = wT + ((size_t)(n16 * NKB + kb0)) * 512 + l * 8;
      const unsigned short* xb = x16 + (size_t)(l & 15) * Kp + kb0 * 32 + (l >> 4) * 8;
      f32x4 acc[4];
#pragma unroll
      for (int m = 0; m < 4; ++m) acc[m] = f32x4{0.f, 0.f, 0.f, 0.f};
#pragma unroll 4
      for (int ks = 0; ks < nks; ++ks) {
        const bf16x8 bfr = *(const bf16x8*)(wb + (size_t)ks * 512);
        const bf16x8 a0 = *(const bf16x8*)(xb + ks * 32);
        const bf16x8 a1 = *(const bf16x8*)(xb + ks * 32 + (size_t)16 * Kp);
        const bf16x8 a2 = *(const bf16x8*)(xb + ks * 32 + (size_t)32 * Kp);
        const bf16x8 a3 = *(const bf16x8*)(xb + ks * 32 + (size_t)48 * Kp);
        acc[0] = __builtin_amdgcn_mfma_f32_16x16x32_bf16(a0, bfr, acc[0], 0, 0, 0);
        acc[1] = __builtin_amdgcn_mfma_f32_16x16x32_bf16(a1, bfr, acc[1], 0, 0, 0);
        acc[2] = __builtin_amdgcn_mfma_f32_16x16x32_bf16(a2, bfr, acc[2], 0, 0, 0);
        acc[3] = __builtin_amdgcn_mfma_f32_16x16x32_bf16(a3, bfr, acc[3], 0, 0, 0);
      }
      const int ncol = n16 * 16 + (l & 15);
      const int rb = (l >> 4) * 4;
#pragma unroll
      for (int mb = 0; mb < 4; ++mb)
#pragma unroll
        for (int r = 0; r < 4; ++r)
          zout[(size_t)(mb * 16 + rb + r) * ZC + ncol] = acc[mb][r];
    }
  } else if (wg < 320) {
    if (t < NT) do_fl2(p, sm, wg - 256, tid);
  } else if (wg < 328) {
    if (t + 1 < NT) do_s1(p, ws + M2_PM1, t + 1, wg - 320, tid);
  }
}

template<bool USEMEM>
__device__ void phase2_2(const Params& p, float* sm, int wg, int tid, int t) {
  float* ws = p.ws;
  unsigned short* u16 = (unsigned short*)(ws + M2_FEND);
  if (wg < 64) {
    if (t < NT) {
      const int b = wg;
      float* h_sh = sm;
      float* q_sh = sm + 1024;
      float* red  = sm + 1152;
      float* w_sh = sm + 1408;
      float* c_a  = ws + M2_CA;
      float* h_a  = ws + M2_HA;
      unsigned short* xA = u16 + M2_X16A + (size_t)b * KA;
      unsigned short* xD = u16 + M2_X16D + (size_t)b * KD;
      const float* za0 = ws + M2_ZAP + (size_t)b * ZC;
      const float* za1 = za0 + (size_t)NB * ZC;
#pragma unroll
      for (int j = 0; j < 4; ++j) {
        const int g = tid + j * 256;
        const float zi = p.ab[g]        + za0[g]        + za1[g];
        const float zf = p.ab[1024 + g] + za0[1024 + g] + za1[1024 + g];
        const float zg = p.ab[2048 + g] + za0[2048 + g] + za1[2048 + g];
        const float zo = p.ab[3072 + g] + za0[3072 + g] + za1[3072 + g];
        const float cold = c_a[b * NA + g];
        const float iv = sigm(zi), fv = sigm(zf), gv = tanh_t(zg), ov = sigm(zo);
        const float c2 = fv * cold + iv * gv;
        const float h2 = ov * tanh_t(c2);
        c_a[b * NA + g] = c2;
        h_a[b * NA + g] = h2;
        h_sh[g] = h2;
        xA[768 + g] = f2bf(h2);
        xD[g]       = f2bf(h2);
      }
      __syncthreads();
      {
        const int ad = tid & 127, kh = tid >> 7;
        float acc = 0.f;
        const float* wqp = p.wq + ad;
#pragma unroll 8
        for (int k = kh * 512; k < kh * 512 + 512; ++k) acc += h_sh[k] * wqp[(size_t)k * NAD];
        red[tid] = acc;
      }
      __syncthreads();
      if (tid < 128) q_sh[tid] = red[tid] + red[tid + 128];
      __syncthreads();
      float ev = 0.f;
      {
        const unsigned short* flp = u16 + M2_FL16 + (size_t)(b * NAD) * NS + tid;
#pragma unroll 8
        for (int ad = 0; ad < NAD; ++ad)
          ev += tanh_t(q_sh[ad] + bf2f(flp[(size_t)ad * NS])) * p.vatt[ad];
      }
      red[tid] = ev; __syncthreads();
      for (int off = 128; off > 0; off >>= 1) {
        if (tid < off) red[tid] = fmaxf(red[tid], red[tid + off]);
        __syncthreads();
      }
      const float mx = red[0];
      __syncthreads();
      const float ex = __expf(ev - mx);
      red[tid] = ex; __syncthreads();
      for (int off = 128; off > 0; off >>= 1) {
        if (tid < off) red[tid] += red[tid + off];
        __syncthreads();
      }
      const float wv = ex / red[0];
      w_sh[tid] = wv;
      ws[M2_WGL + b * NS + tid] = wv;
      ws[M2_WCU + b * NS + tid] += wv;
      p.out[ALIGN_BASE + (size_t)b * NT * NS + (size_t)t * NS + tid] = wv;
      __syncthreads();
      {
        float a0 = 0.f, a1 = 0.f;
        if constexpr (USEMEM) {
          const unsigned short* mb16 = u16 + M2_MEM16 + (size_t)b * NS * NE;
#pragma unroll 8
          for (int ss = 0; ss < NS; ++ss) {
            const float wcur = w_sh[ss];
            a0 += wcur * bf2f(mb16[(size_t)ss * NE + tid]);
            a1 += wcur * bf2f(mb16[(size_t)ss * NE + tid + 256]);
          }
        } else {
          const float* mb = p.memory + (size_t)b * NS * NE;
#pragma unroll 8
          for (int ss = 0; ss < NS; ++ss) {
            const float wcur = w_sh[ss];
            a0 += wcur * mb[(size_t)ss * NE + tid];
            a1 += wcur * mb[(size_t)ss * NE + tid + 256];
          }
        }
        float* cdst = ws + M2_CTX + (t & 1) * (NB * NE) + b * NE;
        cdst[tid] = a0;
        cdst[tid + 256] = a1;
        xA[256 + tid]  = f2bf(a0);
        xA[512 + tid]  = f2bf(a1);
        xD[1024 + tid] = f2bf(a0);
        xD[1280 + tid] = f2bf(a1);
      }
    }
  } else if (wg < 128) {
    if (t >= 1) {
      const int b = wg - 64;
      const int tm1 = t - 1;
      float* h_sh = sm;
      float* red  = sm + 1024;
      float* c_d  = ws + M2_CD;
      float* h_d  = ws + M2_HD;
      unsigned short* xD = u16 + M2_X16D + (size_t)b * KD;
      const float* zd0 = ws + M2_ZDP + (size_t)b * ZC;
      const float* zd1 = zd0 + (size_t)NB * ZC;
#pragma unroll
      for (int j = 0; j < 4; ++j) {
        const int g = tid + j * 256;
        const float zi = p.db[g]        + zd0[g]        + zd1[g];
        const float zf = p.db[1024 + g] + zd0[1024 + g] + zd1[1024 + g];
        const float zg = p.db[2048 + g] + zd0[2048 + g] + zd1[2048 + g];
        const float zo = p.db[3072 + g] + zd0[3072 + g] + zd1[3072 + g];
        const float cold = c_d[b * ND + g];
        const float iv = sigm(zi), fv = sigm(zf), gv = tanh_t(zg), ov = sigm(zo);
        const float c2 = fv * cold + iv * gv;
        const float h2 = ov * tanh_t(c2);
        c_d[b * ND + g] = c2;
        h_d[b * ND + g] = h2;
        h_sh[g] = h2;
        xD[1536 + g] = f2bf(h2);
      }
      __syncthreads();
      const float* ctxp = ws + M2_CTX + (tm1 & 1) * (NB * NE) + b * NE;
      {
        float acc = 0.f;
        for (int k = tid; k < 1536; k += 256) {
          const float v = (k < 1024) ? h_sh[k] : ctxp[k - 1024];
          acc += v * p.gatew[k];
        }
        red[tid] = acc;
      }
      __syncthreads();
      for (int off = 128; off > 0; off >>= 1) {
        if (tid < off) red[tid] += red[tid + off];
        __syncthreads();
      }
      if (tid == 0) p.out[STOP_BASE + (size_t)b * NT + tm1] = sigm(red[0] + p.gateb[0]);
      __syncthreads();
      if (tid < 240) {
        const int m = tid % 80, kh = tid / 80;
        float acc = 0.f;
#pragma unroll 4
        for (int k = kh * 512; k < kh * 512 + 512; ++k) {
          const float v = (k < 1024) ? h_sh[k] : ctxp[k - 1024];
          acc += v * p.projw[(size_t)k * 80 + m];
        }
        red[kh * 80 + m] = acc;
      }
      __syncthreads();
      if (tid < 80) {
        const float mval = p.projb[tid] + red[tid] + red[80 + tid] + red[160 + tid];
        p.out[MEL_BASE + (size_t)b * NT * NMEL + (size_t)tm1 * NMEL + tid] = mval;
      }
    }
  } else if (wg < 144) {
    if (t + 1 < NT)
      do_s2<2>(p, ws + M2_PM1, nullptr, u16 + M2_X16A, wg - 128, tid);
  }
}

template<bool USEMEM>
__global__ __launch_bounds__(256, 2) void taco2(Params p) {
  cg::grid_group grid = cg::this_grid();
  const int wg  = blockIdx.x;
  const int tid = threadIdx.x;
  __shared__ float sm[SMN];

  pre_a2<USEMEM>(p, sm, wg, tid);
  grid.sync();
  if (wg >= 128 && wg < 144)
    do_s2<2>(p, p.ws + M2_PM1, nullptr,
             (unsigned short*)(p.ws + M2_FEND) + M2_X16A, wg - 128, tid);
  grid.sync();
  unsigned* bar = (unsigned*)(p.ws + M2_BAR);
  for (int t = 0; t <= NT; ++t) {
    phase1_2(p, sm, wg, tid, t);
    gbar(bar, wg, tid);
    phase2_2<USEMEM>(p, sm, wg, tid, t);
    gbar(bar, wg, tid);
  }
}

extern "C" void kernel_launch(void* const* d_in, const int* in_sizes, int n_in,
                              void* d_out, int out_size, void* d_ws, size_t ws_size,
                              hipStream_t stream) {
  (void)in_sizes; (void)n_in; (void)out_size;
  Params prm;
  prm.memory = (const float*)d_in[0];
  prm.mel    = (const float*)d_in[1];
  prm.pw1    = (const float*)d_in[2];
  prm.pw2    = (const float*)d_in[3];
  prm.awx    = (const float*)d_in[4];
  prm.awh    = (const float*)d_in[5];
  prm.ab     = (const float*)d_in[6];
  prm.wq     = (const float*)d_in[7];
  prm.wm     = (const float*)d_in[8];
  prm.lconv  = (const float*)d_in[9];
  prm.wloc   = (const float*)d_in[10];
  prm.vatt   = (const float*)d_in[11];
  prm.dwx    = (const float*)d_in[12];
  prm.dwh    = (const float*)d_in[13];
  prm.db     = (const float*)d_in[14];
  prm.projw  = (const float*)d_in[15];
  prm.projb  = (const float*)d_in[16];
  prm.gatew  = (const float*)d_in[17];
  prm.gateb  = (const float*)d_in[18];
  prm.out = (float*)d_out;
  prm.ws  = (float*)d_ws;

  void* args[] = { &prm };
  hipError_t err = hipErrorUnknown;
  if (ws_size >= (size_t)M3_BYTES) {
    (void)hipFuncSetAttribute((const void*)taco3,
                              hipFuncAttributeMaxDynamicSharedMemorySize, DYN_LDS);
    err = hipLaunchCooperativeKernel((void*)taco3, dim3(G3), dim3(T3),
                                     args, DYN_LDS, stream);
  }
  if (err != hipSuccess && ws_size >= (size_t)M2_BYTES)
    err = hipLaunchCooperativeKernel((void*)taco2<true>, dim3(G), dim3(256), args, 0, stream);
  if (err != hipSuccess && ws_size >= (size_t)M2_BYTES_NM)
    err = hipLaunchCooperativeKernel((void*)taco2<false>, dim3(G), dim3(256), args, 0, stream);
}

// Round 13
// 98110.968 us; speedup vs baseline: 1.5346x; 1.5346x over previous
//
#include <hip/hip_runtime.h>
#include <hip/hip_cooperative_groups.h>

namespace cg = cooperative_groups;

constexpr int NB   = 64;
constexpr int NS   = 256;
constexpr int NT   = 500;
constexpr int NMEL = 80;
constexpr int NE   = 512;
constexpr int NP   = 256;
constexpr int NA   = 1024;
constexpr int ND   = 1024;
constexpr int NAD  = 128;
constexpr int ZC   = 4096;
constexpr int KA   = 1792;
constexpr int KD   = 2560;
constexpr int NKA  = 11;     // legacy
constexpr int NKD  = 16;     // legacy
constexpr int G    = 512;

constexpr int SMN  = 5280;   // legacy static LDS floats

// ---- legacy layout (MODE 0/1) ----
constexpr int OFF_KEYST = 0;
constexpr int OFF_FL    = OFF_KEYST + NB * NAD * NS;
constexpr int OFF_W2    = OFF_FL + NB * NAD * NS;
constexpr int OFF_ZA    = OFF_W2 + 62 * NAD;
constexpr int OFF_ZD    = OFF_ZA + NB * ZC;
constexpr int OFF_HA    = OFF_ZD + NB * ZC;
constexpr int OFF_CA    = OFF_HA + NB * NA;
constexpr int OFF_HD    = OFF_CA + NB * NA;
constexpr int OFF_CD    = OFF_HD + NB * ND;
constexpr int OFF_CTX   = OFF_CD + NB * ND;
constexpr int OFF_WGL   = OFF_CTX + 2 * NB * NE;
constexpr int OFF_WCU   = OFF_WGL + NB * NS;
constexpr int OFF_P     = OFF_WCU + NB * NS;
constexpr int OFF_PM1   = OFF_P + 2 * NB * NP;
constexpr int WS_BASE   = OFF_PM1 + NB * NP;
constexpr int ZERO_CNT  = OFF_P - OFF_HA;
constexpr int OFF_ZAP   = WS_BASE;
constexpr int OFF_ZDP   = OFF_ZAP + NKA * NB * ZC;
constexpr long WS_FULL  = (long)OFF_ZDP + (long)NKD * NB * ZC;

// ---- MODE2 layout (fallback) ----
constexpr long M2_W2   = 0;
constexpr long M2_ZAP  = M2_W2 + 62 * NAD;
constexpr long M2_ZDP  = M2_ZAP + 2 * NB * ZC;
constexpr long M2_HA   = M2_ZDP + 2 * NB * ZC;
constexpr long M2_CA   = M2_HA + NB * NA;
constexpr long M2_HD   = M2_CA + NB * NA;
constexpr long M2_CD   = M2_HD + NB * ND;
constexpr long M2_CTX  = M2_CD + NB * ND;
constexpr long M2_WGL  = M2_CTX + 2 * NB * NE;
constexpr long M2_WCU  = M2_WGL + NB * NS;
constexpr long M2_PM1  = M2_WCU + NB * NS;
constexpr long M2_ZCNT = M2_PM1 - M2_HA;
constexpr long M2_BAR  = M2_PM1 + NB * NP;
constexpr long M2_FEND = M2_BAR + 1024;
constexpr long M2_WAT   = 0;
constexpr long M2_WDT   = M2_WAT + (long)ZC * KA;
constexpr long M2_X16A  = M2_WDT + (long)ZC * KD;
constexpr long M2_X16D  = M2_X16A + (long)NB * KA;
constexpr long M2_K16   = M2_X16D + (long)NB * KD;
constexpr long M2_FL16  = M2_K16 + (long)NB * NAD * NS;
constexpr long M2_MEM16 = M2_FL16 + (long)NB * NAD * NS;
constexpr long M2_UEND_NM = M2_MEM16;
constexpr long M2_UEND    = M2_MEM16 + (long)NB * NS * NE;
constexpr long M2_BYTES_NM = M2_FEND * 4 + M2_UEND_NM * 2;
constexpr long M2_BYTES    = M2_FEND * 4 + M2_UEND * 2;

// ---- MODE3 layout: LDS-resident weights ----
constexpr int G3 = 256, T3 = 512;
constexpr long M3_W2   = 0;                         // [62][128]
constexpr long M3_ZA   = M3_W2 + 62 * NAD;          // [64][4096]
constexpr long M3_ZD   = M3_ZA + NB * ZC;           // [64][4096]
constexpr long M3_CTX  = M3_ZD + NB * ZC;           // [2][64][512]
constexpr long M3_WGL  = M3_CTX + 2 * NB * NE;      // [64][256]
constexpr long M3_WCU  = M3_WGL + NB * NS;
constexpr long M3_PM1  = M3_WCU + NB * NS;          // [64][256]
constexpr long M3_BAR  = M3_PM1 + NB * NP;          // 1024 uints
constexpr long M3_FEND = M3_BAR + 1024;
// ushorts at (ushort*)(ws + M3_FEND)
constexpr long M3_WAT  = 0;                          // [256][56][512]
constexpr long M3_WDT  = M3_WAT + (long)ZC * KA;     // [256][80][512]
constexpr long M3_X16A = M3_WDT + (long)ZC * KD;     // [64][1792]
constexpr long M3_X16D = M3_X16A + (long)NB * KA;    // [64][2560]
constexpr long M3_K16  = M3_X16D + (long)NB * KD;    // [64][128][256]
constexpr long M3_FL16 = M3_K16 + (long)NB * NAD * NS;
constexpr long M3_WQ16 = M3_FL16 + (long)NB * NAD * NS; // [1024][128]
constexpr long M3_MEMT = M3_WQ16 + (long)NA * NAD;   // [64][512][256] transposed
constexpr long M3_UEND = M3_MEMT + (long)NB * NE * NS;
constexpr long M3_BYTES = M3_FEND * 4 + M3_UEND * 2; // ~64.2 MB
constexpr int  DYN_LDS  = 159744;                    // 57344 + 81920 + 20480

constexpr long MEL_BASE   = 0;
constexpr long STOP_BASE  = (long)NB * NT * NMEL;
constexpr long ALIGN_BASE = STOP_BASE + (long)NB * NT;

typedef __attribute__((ext_vector_type(8))) short bf16x8;
typedef __attribute__((ext_vector_type(4))) float f32x4;

struct Params {
  const float *memory, *mel, *pw1, *pw2, *awx, *awh, *ab, *wq, *wm,
              *lconv, *wloc, *vatt, *dwx, *dwh, *db, *projw, *projb, *gatew, *gateb;
  float *out, *ws;
};

__device__ __forceinline__ float sigm(float x) { return 1.f / (1.f + __expf(-x)); }
__device__ __forceinline__ float tanh_t(float x) {
  x = fminf(fmaxf(x, -15.f), 15.f);
  const float a = __expf(2.f * x);
  return (a - 1.f) / (a + 1.f);
}
__device__ __forceinline__ unsigned short f2bf(float x) {
  union { float f; unsigned u; } c; c.f = x;
  const unsigned r = c.u + 0x7FFFu + ((c.u >> 16) & 1u);
  return (unsigned short)(r >> 16);
}
__device__ __forceinline__ float bf2f(unsigned short v) {
  union { unsigned u; float f; } c; c.u = (unsigned)v << 16;
  return c.f;
}

// ---- fenced grid barrier, 32-block leaves (512-grid legacy) ----
__device__ __forceinline__ void gbar(unsigned* bar, int wg, int tid) {
  __syncthreads();
  if (tid == 0) {
    unsigned* gen  = bar;
    unsigned* root = bar + 32;
    unsigned* leaf = bar + 64 + (wg >> 5) * 32;
    const unsigned g = __hip_atomic_load(gen, __ATOMIC_RELAXED, __HIP_MEMORY_SCOPE_AGENT);
    __threadfence();
    const unsigned lo = __hip_atomic_fetch_add(leaf, 1u, __ATOMIC_ACQ_REL,
                                               __HIP_MEMORY_SCOPE_AGENT);
    if (lo == 31) {
      __hip_atomic_store(leaf, 0u, __ATOMIC_RELAXED, __HIP_MEMORY_SCOPE_AGENT);
      const unsigned ro = __hip_atomic_fetch_add(root, 1u, __ATOMIC_ACQ_REL,
                                                 __HIP_MEMORY_SCOPE_AGENT);
      if (ro == 15) {
        __hip_atomic_store(root, 0u, __ATOMIC_RELAXED, __HIP_MEMORY_SCOPE_AGENT);
        __hip_atomic_fetch_add(gen, 1u, __ATOMIC_ACQ_REL, __HIP_MEMORY_SCOPE_AGENT);
      }
    }
    while (__hip_atomic_load(gen, __ATOMIC_RELAXED, __HIP_MEMORY_SCOPE_AGENT) == g)
      __builtin_amdgcn_s_sleep(16);
    __threadfence();
  }
  __syncthreads();
}

// ---- fenced grid barrier, 16 leaves x 16 blocks (MODE3, 256-grid) ----
__device__ __forceinline__ void gbar3(unsigned* bar, int wg, int tid) {
  __syncthreads();
  if (tid == 0) {
    unsigned* gen  = bar;
    unsigned* root = bar + 32;
    unsigned* leaf = bar + 64 + (wg >> 4) * 32;
    const unsigned g = __hip_atomic_load(gen, __ATOMIC_RELAXED, __HIP_MEMORY_SCOPE_AGENT);
    __threadfence();
    const unsigned lo = __hip_atomic_fetch_add(leaf, 1u, __ATOMIC_ACQ_REL,
                                               __HIP_MEMORY_SCOPE_AGENT);
    if (lo == 15) {
      __hip_atomic_store(leaf, 0u, __ATOMIC_RELAXED, __HIP_MEMORY_SCOPE_AGENT);
      const unsigned ro = __hip_atomic_fetch_add(root, 1u, __ATOMIC_ACQ_REL,
                                                 __HIP_MEMORY_SCOPE_AGENT);
      if (ro == 15) {
        __hip_atomic_store(root, 0u, __ATOMIC_RELAXED, __HIP_MEMORY_SCOPE_AGENT);
        __hip_atomic_fetch_add(gen, 1u, __ATOMIC_ACQ_REL, __HIP_MEMORY_SCOPE_AGENT);
      }
    }
    while (__hip_atomic_load(gen, __ATOMIC_RELAXED, __HIP_MEMORY_SCOPE_AGENT) == g)
      __builtin_amdgcn_s_sleep(8);
    __threadfence();
  }
  __syncthreads();
}

// prenet stage 1 (call with tid<256)
__device__ void do_s1(const Params& p, float* pm1, int tnext, int wl, int tid) {
  const int col = tid;
  for (int i = 0; i < 8; ++i) {
    const int b = wl * 8 + i;
    const float* mrow = p.mel + ((size_t)b * NT + tnext) * NMEL;
    float acc = 0.f;
    for (int k = 0; k < NMEL; ++k) acc += mrow[k] * p.pw1[k * NP + col];
    pm1[b * NP + col] = fmaxf(acc, 0.f);
  }
}

// prenet stage 2 (call with tid<256)
template<int MODE>
__device__ void do_s2(const Params& p, const float* pm1, float* pdst,
                      unsigned short* xA, int wl, int tid) {
  const int col = tid;
  for (int i = 0; i < 4; ++i) {
    const int b = wl * 4 + i;
    const float* pr = pm1 + b * NP;
    float acc = 0.f;
    for (int k = 0; k < NP; ++k) acc += pr[k] * p.pw2[k * NP + col];
    const float v = fmaxf(acc, 0.f);
    if constexpr (MODE >= 2) xA[(size_t)b * KA + col] = f2bf(v);
    else                     pdst[b * NP + col] = v;
  }
}

// ======================= MODE3 =======================
__device__ void do_fl3(const Params& p, float* scr, unsigned short* u16, int wg, int tid) {
  float* ws = p.ws;
  float* chunk = scr;              // 3968 f
  float* wp = scr + 3968;          // [2][2][288]
  const int hf = tid >> 8, ts = tid & 255;
  const int b = (wg - 144) * 2 + hf;
  float* wp0 = wp + hf * 576;
  float* wp1 = wp0 + 288;
  for (int i = ts; i < 288; i += 256) { wp0[i] = 0.f; wp1[i] = 0.f; }
  __syncthreads();
  wp0[15 + ts] = ws[M3_WGL + b * NS + ts];
  wp1[15 + ts] = ws[M3_WCU + b * NS + ts];
  __syncthreads();
  float x0[31], x1[31];
#pragma unroll
  for (int k = 0; k < 31; ++k) { x0[k] = wp0[ts + k]; x1[k] = wp1[ts + k]; }
  const unsigned short* kb16 = u16 + M3_K16 + (size_t)(b * NAD) * NS + ts;
  unsigned short* fb16 = u16 + M3_FL16 + (size_t)(b * NAD) * NS + ts;
  const float* W2g = ws + M3_W2;
  for (int ch = 0; ch < 2; ++ch) {
    for (int i = tid; i < 62 * 64; i += T3) {
      const int k2 = i >> 6, adl = i & 63;
      chunk[i] = W2g[k2 * NAD + ch * 64 + adl];
    }
    __syncthreads();
    for (int adl = 0; adl < 64; ++adl) {
      const int ad = ch * 64 + adl;
      float acc = bf2f(kb16[(size_t)ad * NS]);
#pragma unroll
      for (int k = 0; k < 31; ++k)
        acc = fmaf(x0[k], chunk[(2 * k) * 64 + adl],
              fmaf(x1[k], chunk[(2 * k + 1) * 64 + adl], acc));
      fb16[(size_t)ad * NS] = f2bf(acc);
    }
    __syncthreads();
  }
}

__device__ void attn3(const Params& p, float* scr, unsigned short* u16,
                      int b, int tid, int t, float& c0, float& c1) {
  if (t >= NT) return;
  float* ws = p.ws;
  float* h_sh = scr;
  float* red  = scr + 1024;
  float* q_sh = scr + 1536;
  float* w_sh = scr + 1664;
  unsigned short* xA = u16 + M3_X16A + (size_t)b * KA;
  unsigned short* xD = u16 + M3_X16D + (size_t)b * KD;
  const float* za = ws + M3_ZA + (size_t)b * ZC;
#pragma unroll
  for (int j = 0; j < 2; ++j) {
    const int g = tid + j * 512;
    const float zi = p.ab[g] + za[g];
    const float zf = p.ab[1024 + g] + za[1024 + g];
    const float zg = p.ab[2048 + g] + za[2048 + g];
    const float zo = p.ab[3072 + g] + za[3072 + g];
    float& cc = j ? c1 : c0;
    const float iv = sigm(zi), fv = sigm(zf), gv = tanh_t(zg), ov = sigm(zo);
    const float cn = fv * cc + iv * gv;
    const float h2 = ov * tanh_t(cn);
    cc = cn;
    h_sh[g] = h2;
    xA[768 + g] = f2bf(h2);
    xD[g]       = f2bf(h2);
  }
  __syncthreads();
  // query: ad 128 x 4-way ksplit (bf16 wq)
  {
    const int ad = tid & 127, kh = tid >> 7;
    const unsigned short* wqp = u16 + M3_WQ16 + ad;
    float acc = 0.f;
#pragma unroll 16
    for (int k = kh * 256; k < kh * 256 + 256; ++k) acc += h_sh[k] * bf2f(wqp[(size_t)k * NAD]);
    red[tid] = acc;
  }
  __syncthreads();
  if (tid < 128) q_sh[tid] = red[tid] + red[tid + 128] + red[tid + 256] + red[tid + 384];
  __syncthreads();
  // energies: s 256 x 2-way ad-split
  float evp = 0.f;
  {
    const int s = tid & 255, hf = tid >> 8;
    const unsigned short* flp = u16 + M3_FL16 + (size_t)(b * NAD + hf * 64) * NS + s;
    const float* qs = q_sh + hf * 64;
    const float* va = p.vatt + hf * 64;
#pragma unroll 8
    for (int ad = 0; ad < 64; ++ad)
      evp += tanh_t(qs[ad] + bf2f(flp[(size_t)ad * NS])) * va[ad];
  }
  red[tid] = evp;
  __syncthreads();
  float evs = 0.f;
  if (tid < 256) evs = red[tid] + red[tid + 256];
  __syncthreads();
  if (tid < 256) red[tid] = evs;
  __syncthreads();
  for (int off = 128; off > 0; off >>= 1) {
    if (tid < off) red[tid] = fmaxf(red[tid], red[tid + off]);
    __syncthreads();
  }
  const float mx = red[0];
  __syncthreads();
  const float ex = (tid < 256) ? __expf(evs - mx) : 0.f;
  red[tid] = ex;
  __syncthreads();
  for (int off = 128; off > 0; off >>= 1) {
    if (tid < off) red[tid] += red[tid + off];
    __syncthreads();
  }
  const float sden = red[0];
  if (tid < 256) {
    const float wv = ex / sden;
    w_sh[tid] = wv;
    ws[M3_WGL + b * NS + tid] = wv;
    ws[M3_WCU + b * NS + tid] += wv;
    p.out[ALIGN_BASE + (size_t)b * NT * NS + (size_t)t * NS + tid] = wv;
  }
  __syncthreads();
  // context from transposed bf16 memory: e = tid, contiguous s-run
  {
    const int e = tid;
    const unsigned short* mrow = u16 + M3_MEMT + ((size_t)b * NE + e) * NS;
    float a0 = 0.f;
#pragma unroll 4
    for (int sc = 0; sc < 32; ++sc) {
      const bf16x8 v = *(const bf16x8*)(mrow + sc * 8);
#pragma unroll
      for (int j = 0; j < 8; ++j) a0 += w_sh[sc * 8 + j] * bf2f((unsigned short)v[j]);
    }
    float* cdst = ws + M3_CTX + (t & 1) * (NB * NE) + b * NE;
    cdst[e] = a0;
    xA[256 + e]  = f2bf(a0);
    xD[1024 + e] = f2bf(a0);
  }
}

__device__ void dec3(const Params& p, float* scr, unsigned short* u16,
                     int b, int tid, int t, float& c0, float& c1) {
  if (t < 1) return;
  const int tm1 = t - 1;
  float* ws = p.ws;
  float* h_sh = scr;
  float* red  = scr + 1024;
  unsigned short* xD = u16 + M3_X16D + (size_t)b * KD;
  const float* zd = ws + M3_ZD + (size_t)b * ZC;
#pragma unroll
  for (int j = 0; j < 2; ++j) {
    const int g = tid + j * 512;
    const float zi = p.db[g] + zd[g];
    const float zf = p.db[1024 + g] + zd[1024 + g];
    const float zg = p.db[2048 + g] + zd[2048 + g];
    const float zo = p.db[3072 + g] + zd[3072 + g];
    float& cc = j ? c1 : c0;
    const float iv = sigm(zi), fv = sigm(zf), gv = tanh_t(zg), ov = sigm(zo);
    const float cn = fv * cc + iv * gv;
    const float h2 = ov * tanh_t(cn);
    cc = cn;
    h_sh[g] = h2;
    xD[1536 + g] = f2bf(h2);
  }
  __syncthreads();
  const float* ctxf = ws + M3_CTX + (tm1 & 1) * (NB * NE) + b * NE;
  // stop gate
  red[tid] = h_sh[tid] * p.gatew[tid] + h_sh[tid + 512] * p.gatew[tid + 512]
           + ctxf[tid] * p.gatew[tid + 1024];
  __syncthreads();
  for (int off = 256; off > 0; off >>= 1) {
    if (tid < off) red[tid] += red[tid + off];
    __syncthreads();
  }
  if (tid == 0) p.out[STOP_BASE + (size_t)b * NT + tm1] = sigm(red[0] + p.gateb[0]);
  __syncthreads();
  // mel projection: 80 m x 6-way ksplit
  if (tid < 480) {
    const int m = tid % 80, kh = tid / 80;
    float acc = 0.f;
#pragma unroll 8
    for (int k = kh * 256; k < kh * 256 + 256; ++k) {
      const float v = (k < 1024) ? h_sh[k] : ctxf[k - 1024];
      acc += v * p.projw[(size_t)k * 80 + m];
    }
    red[kh * 80 + m] = acc;
  }
  __syncthreads();
  if (tid < 80) {
    float mval = p.projb[tid];
#pragma unroll
    for (int kh = 0; kh < 6; ++kh) mval += red[kh * 80 + tid];
    p.out[MEL_BASE + (size_t)b * NT * NMEL + (size_t)tm1 * NMEL + tid] = mval;
  }
}

__global__ __launch_bounds__(512, 1) void taco3(Params p) {
  cg::grid_group grid = cg::this_grid();
  const int wg = blockIdx.x, tid = threadIdx.x;
  extern __shared__ char dynsm[];
  unsigned short* wA_l = (unsigned short*)dynsm;              // 57344 B
  unsigned short* wD_l = (unsigned short*)(dynsm + 57344);    // 81920 B
  float* scr = (float*)(dynsm + 139264);                      // 20480 B scratch
  float* ws = p.ws;
  unsigned short* u16 = (unsigned short*)(ws + M3_FEND);

  // ---------------- pre-phase A ----------------
  {
    const long gid = (long)wg * T3 + tid, gstr = (long)G3 * T3;
    for (long i = gid; i < 98304; i += gstr) ws[M3_CTX + i] = 0.f;  // ctx+w+wcum
    if (wg == 0) for (int i = tid; i < 1024; i += T3) ((unsigned*)(ws + M3_BAR))[i] = 0;
    for (long i = gid; i < 62 * NAD; i += gstr) {
      const int k2 = (int)(i >> 7), ad = (int)(i & 127);
      float a = 0.f;
      for (int f = 0; f < 32; ++f) a += p.lconv[k2 * 32 + f] * p.wloc[f * NAD + ad];
      ws[M3_W2 + i] = a;
    }
    for (long i = gid; i < (long)NB * KA + (long)NB * KD; i += gstr) u16[M3_X16A + i] = 0;
    for (long i = gid; i < (long)NA * NAD; i += gstr) u16[M3_WQ16 + i] = f2bf(p.wq[i]);
    for (long i = gid; i < (long)NB * NE * NS; i += gstr) {
      const int s = (int)(i & 255);
      const long be = i >> 8;
      const int e = (int)(be & 511), b = (int)(be >> 9);
      u16[M3_MEMT + i] = f2bf(p.memory[((size_t)b * NS + s) * NE + e]);
    }
    // keysT bf16: 4 WGs per b, 64-s chunk, 16 ad-groups of 8
    {
      const int b = wg >> 2, s0 = (wg & 3) * 64;
      const int sl = tid & 31, adg = tid >> 5;  // 0..15
      const float* wmb = p.wm + adg * 8;
      for (int so = 0; so < 64; so += 32) {
        const float* mrow = p.memory + (size_t)(b * NS + s0 + so + sl) * NE;
        float acc[8];
#pragma unroll
        for (int j = 0; j < 8; ++j) acc[j] = 0.f;
        for (int k = 0; k < NE; ++k) {
          const float mv = mrow[k];
          const float* wr = wmb + (size_t)k * NAD;
#pragma unroll
          for (int j = 0; j < 8; ++j) acc[j] += mv * wr[j];
        }
#pragma unroll
        for (int j = 0; j < 8; ++j)
          u16[M3_K16 + (size_t)(b * NAD + adg * 8 + j) * NS + s0 + so + sl] = f2bf(acc[j]);
      }
    }
    // pack bf16 weight fragments -> global WAT/WDT (tiles of 32k x 64n)
    for (int tile = wg; tile < 3584 + 5120; tile += G3) {
      const bool iA = tile < 3584;
      const int tt = iA ? tile : tile - 3584;
      const int NKB = iA ? 56 : 80;
      const int nt4 = tt / NKB, kb = tt % NKB;
      const int kx = iA ? 768 : 1536;
      float4 v0{}, v1{};
      if (tid < 256) {
        const int r = tid >> 3, cgp = (tid & 7) * 8;
        const int k = kb * 32 + r;
        const float* src = iA
            ? (k < kx ? p.awx + (size_t)k * ZC : p.awh + (size_t)(k - kx) * ZC)
            : (k < kx ? p.dwx + (size_t)k * ZC : p.dwh + (size_t)(k - kx) * ZC);
        const float* sp = src + nt4 * 64 + cgp;
        v0 = *(const float4*)sp;
        v1 = *(const float4*)(sp + 4);
      }
      __syncthreads();
      if (tid < 256) {
        const int r = tid >> 3, cgp = (tid & 7) * 8;
        *(float4*)(scr + r * 64 + cgp)     = v0;
        *(float4*)(scr + r * 64 + cgp + 4) = v1;
      }
      __syncthreads();
      if (tid < 256) {
        const int blk = tid >> 6, l = tid & 63;
        const int n16 = nt4 * 4 + blk;
        bf16x8 pk;
#pragma unroll
        for (int j = 0; j < 8; ++j)
          pk[j] = (short)f2bf(scr[((l >> 4) * 8 + j) * 64 + blk * 16 + (l & 15)]);
        unsigned short* dst = u16 + (iA ? M3_WAT : M3_WDT)
                            + ((size_t)(n16 * NKB + kb)) * 512 + l * 8;
        *(bf16x8*)dst = pk;
      }
      __syncthreads();
    }
    if (wg >= 176 && wg < 184 && tid < 256) do_s1(p, ws + M3_PM1, 0, wg - 176, tid);
  }
  grid.sync();
  // ---------------- pre-phase B: LDS-stage weights; s2(0) ----------------
  {
    const float4* srcA = (const float4*)(u16 + M3_WAT + (size_t)wg * 56 * 512);
    float4* dA = (float4*)wA_l;
    for (int i = tid; i < 3584; i += T3) dA[i] = srcA[i];
    const float4* srcD = (const float4*)(u16 + M3_WDT + (size_t)wg * 80 * 512);
    float4* dD = (float4*)wD_l;
    for (int i = tid; i < 5120; i += T3) dD[i] = srcD[i];
    if (wg >= 128 && wg < 144 && tid < 256)
      do_s2<3>(p, ws + M3_PM1, nullptr, u16 + M3_X16A, wg - 128, tid);
  }
  grid.sync();

  float c0 = 0.f, c1 = 0.f;   // recurrent cell state in registers (attn/dec roles)
  unsigned* bar = (unsigned*)(ws + M3_BAR);
  for (int t = 0; t <= NT; ++t) {
    // ========== phase 1 ==========
    {
      const int wid = tid >> 6, l = tid & 63;
      if (wid < 4) {
        if (t < NT) {  // A-GEMM: wave = M-frag, n16 = wg
          const unsigned short* xb = u16 + M3_X16A
              + (size_t)(wid * 16 + (l & 15)) * KA + (l >> 4) * 8;
          f32x4 acc{0.f, 0.f, 0.f, 0.f};
#pragma unroll 8
          for (int ks = 0; ks < 56; ++ks) {
            const bf16x8 bfr = *(const bf16x8*)(wA_l + ks * 512 + l * 8);
            const bf16x8 a   = *(const bf16x8*)(xb + ks * 32);
            acc = __builtin_amdgcn_mfma_f32_16x16x32_bf16(a, bfr, acc, 0, 0, 0);
          }
          const int ncol = wg * 16 + (l & 15), rb = (l >> 4) * 4;
          float* z = ws + M3_ZA;
#pragma unroll
          for (int r = 0; r < 4; ++r) z[(size_t)(wid * 16 + rb + r) * ZC + ncol] = acc[r];
        }
      } else {
        if (t >= 1) {  // D-GEMM
          const int mb = wid - 4;
          const unsigned short* xb = u16 + M3_X16D
              + (size_t)(mb * 16 + (l & 15)) * KD + (l >> 4) * 8;
          f32x4 acc{0.f, 0.f, 0.f, 0.f};
#pragma unroll 8
          for (int ks = 0; ks < 80; ++ks) {
            const bf16x8 bfr = *(const bf16x8*)(wD_l + ks * 512 + l * 8);
            const bf16x8 a   = *(const bf16x8*)(xb + ks * 32);
            acc = __builtin_amdgcn_mfma_f32_16x16x32_bf16(a, bfr, acc, 0, 0, 0);
          }
          const int ncol = wg * 16 + (l & 15), rb = (l >> 4) * 4;
          float* z = ws + M3_ZD;
#pragma unroll
          for (int r = 0; r < 4; ++r) z[(size_t)(mb * 16 + rb + r) * ZC + ncol] = acc[r];
        }
      }
      if (wg >= 144 && wg < 176) {
        if (t < NT) do_fl3(p, scr, u16, wg, tid);
      } else if (wg >= 176 && wg < 184) {
        if (t + 1 < NT && tid < 256) do_s1(p, ws + M3_PM1, t + 1, wg - 176, tid);
      }
    }
    gbar3(bar, wg, tid);
    // ========== phase 2 ==========
    if (wg < 64)       attn3(p, scr, u16, wg, tid, t, c0, c1);
    else if (wg < 128) dec3(p, scr, u16, wg - 64, tid, t, c0, c1);
    else if (wg < 144) {
      if (t + 1 < NT && tid < 256)
        do_s2<3>(p, ws + M3_PM1, nullptr, u16 + M3_X16A, wg - 128, tid);
    }
    gbar3(bar, wg, tid);
  }
}

// ======================= MODE2 (fallback) =======================
template<bool USEMEM>
__device__ void pre_a2(const Params& p, float* sm, int wg, int tid) {
  float* ws = p.ws;
  unsigned short* u16 = (unsigned short*)(ws + M2_FEND);
  const long gid = wg * 256 + tid;
  const long gstr = (long)G * 256;
  for (long i = gid; i < M2_ZCNT; i += gstr) (ws + M2_HA)[i] = 0.f;
  if (wg == 0) for (int i = tid; i < 1024; i += 256) ((unsigned*)(ws + M2_BAR))[i] = 0;
  for (long i = gid; i < 62 * NAD; i += gstr) {
    const int k2 = (int)(i >> 7), ad = (int)(i & 127);
    float acc = 0.f;
    for (int f = 0; f < 32; ++f) acc += p.lconv[k2 * 32 + f] * p.wloc[f * NAD + ad];
    ws[M2_W2 + i] = acc;
  }
  {
    const int b = wg >> 3, s0 = (wg & 7) * 32;
    const int sl = tid & 31, adg = tid >> 5;
    const float* mrow = p.memory + (size_t)(b * NS + s0 + sl) * NE;
    const float* wmb  = p.wm + adg * 16;
    float acc[16];
#pragma unroll
    for (int j = 0; j < 16; ++j) acc[j] = 0.f;
    for (int k = 0; k < NE; ++k) {
      const float mv = mrow[k];
      const float* wr = wmb + (size_t)k * NAD;
#pragma unroll
      for (int j = 0; j < 16; ++j) acc[j] += mv * wr[j];
    }
#pragma unroll
    for (int j = 0; j < 16; ++j)
      u16[M2_K16 + (size_t)(b * NAD + adg * 16 + j) * NS + s0 + sl] = f2bf(acc[j]);
  }
  for (long i = gid; i < (long)NB * KA + (long)NB * KD; i += gstr)
    u16[M2_X16A + i] = 0;
  if constexpr (USEMEM) {
    for (long i = gid; i < (long)NB * NS * NE; i += gstr)
      u16[M2_MEM16 + i] = f2bf(p.memory[i]);
  }
  for (int tile = wg; tile < 3584 + 5120; tile += G) {
    const bool iA = tile < 3584;
    const int tt = iA ? tile : tile - 3584;
    const int NKB = iA ? 56 : 80;
    const int nt4 = tt / NKB, kb = tt % NKB;
    const int kx = iA ? 768 : 1536;
    const int r = tid >> 3, cgp = (tid & 7) * 8;
    const int k = kb * 32 + r;
    const float* src = iA
        ? (k < kx ? p.awx + (size_t)k * ZC : p.awh + (size_t)(k - kx) * ZC)
        : (k < kx ? p.dwx + (size_t)k * ZC : p.dwh + (size_t)(k - kx) * ZC);
    const float* sp = src + nt4 * 64 + cgp;
    const float4 v0 = *(const float4*)sp;
    const float4 v1 = *(const float4*)(sp + 4);
    __syncthreads();
    *(float4*)(sm + r * 64 + cgp)     = v0;
    *(float4*)(sm + r * 64 + cgp + 4) = v1;
    __syncthreads();
    const int blk = tid >> 6, l = tid & 63;
    const int n16 = nt4 * 4 + blk;
    bf16x8 pk;
#pragma unroll
    for (int j = 0; j < 8; ++j)
      pk[j] = (short)f2bf(sm[((l >> 4) * 8 + j) * 64 + blk * 16 + (l & 15)]);
    unsigned short* dst = u16 + (iA ? M2_WAT : M2_WDT)
                        + ((size_t)(n16 * NKB + kb)) * 512 + l * 8;
    *(bf16x8*)dst = pk;
  }
  if (wg >= 320 && wg < 328) do_s1(p, ws + M2_PM1, 0, wg - 320, tid);
}

__device__ void do_fl2(const Params& p, float* sm, int b, int tid) {
  float* ws = p.ws;
  unsigned short* u16 = (unsigned short*)(ws + M2_FEND);
  float* chunk = sm;
  float* wp0 = sm + 4000;
  float* wp1 = sm + 4320;
  for (int i = tid; i < 288; i += 256) { wp0[i] = 0.f; wp1[i] = 0.f; }
  __syncthreads();
  wp0[15 + tid] = ws[M2_WGL + b * NS + tid];
  wp1[15 + tid] = ws[M2_WCU + b * NS + tid];
  __syncthreads();
  float x0[31], x1[31];
#pragma unroll
  for (int k = 0; k < 31; ++k) { x0[k] = wp0[tid + k]; x1[k] = wp1[tid + k]; }
  const unsigned short* kb16 = u16 + M2_K16 + (size_t)(b * NAD) * NS + tid;
  unsigned short* fb16 = u16 + M2_FL16 + (size_t)(b * NAD) * NS + tid;
  const float* W2g = ws + M2_W2;
  for (int ch = 0; ch < 2; ++ch) {
    for (int i = tid; i < 62 * 64; i += 256) {
      const int k2 = i >> 6, adl = i & 63;
      chunk[i] = W2g[k2 * NAD + ch * 64 + adl];
    }
    __syncthreads();
    for (int adl = 0; adl < 64; ++adl) {
      const int ad = ch * 64 + adl;
      float acc = bf2f(kb16[(size_t)ad * NS]);
#pragma unroll
      for (int k = 0; k < 31; ++k)
        acc = fmaf(x0[k], chunk[(2 * k) * 64 + adl],
              fmaf(x1[k], chunk[(2 * k + 1) * 64 + adl], acc));
      fb16[(size_t)ad * NS] = f2bf(acc);
    }
    __syncthreads();
  }
}

__device__ void phase1_2(const Params& p, float* sm, int wg, int tid, int t) {
  float* ws = p.ws;
  unsigned short* u16 = (unsigned short*)(ws + M2_FEND);
  if (wg < 256) {
    const bool isA = wg < 128;
    if ((isA && t < NT) || (!isA && t >= 1)) {
      const int g   = isA ? wg : wg - 128;
      const int kc  = g & 1, nb4 = g >> 1;
      const int NKB = isA ? 56 : 80;
      const int nks = isA ? 28 : 40;
      const int kb0 = kc * nks;
      const int Kp  = isA ? KA : KD;
      const unsigned short* wT  = u16 + (isA ? M2_WAT : M2_WDT);
      const unsigned short* x16 = u16 + (isA ? M2_X16A : M2_X16D);
      float* zout = ws + (isA ? M2_ZAP : M2_ZDP) + (size_t)kc * NB * ZC;
      const int l = tid & 63;
      const int n16 = nb4 * 4 + (tid >> 6);
      const unsigned short* wb = wT + ((size_t)(n16 * NKB + kb0)) * 512 + l * 8;
      const unsigned short* xb = x16 + (size_t)(l & 15) * Kp + kb0 * 32 + (l >> 4) * 8;
      f32x4 acc[4];
#pragma unroll
      for (int m = 0; m < 4; ++m) acc[m] = f32x4{0.f, 0.f, 0.f, 0.f};
#pragma unroll 4
      for (int ks = 0; ks < nks; ++ks) {
        const bf16x8 bfr = *(const bf16x8*)(wb + (size_t)ks * 512);
        const bf16x8 a0 = *(const bf16x8*)(xb + ks * 32);
        const bf16x8 a1 = *(const bf16x8*)(xb + ks * 32 + (size_t)16 * Kp);
        const bf16x8 a2 = *(const bf16x8*)(xb + ks * 32 + (size_t)32 * Kp);
        const bf16x8 a3 = *(const bf16x8*)(xb + ks * 32 + (size_t)48 * Kp);
        acc[0] = __builtin_amdgcn_mfma_f32_16x16x32_bf16(a0, bfr, acc[0], 0, 0, 0);
        acc[1] = __builtin_amdgcn_mfma_f32_16x16x32_bf16(a1, bfr, acc[1], 0, 0, 0);
        acc[2] = __builtin_amdgcn_mfma_f32_16x16x32_bf16(a2, bfr, acc[2], 0, 0, 0);
        acc[3] = __builtin_amdgcn_mfma_f32_16x16x32_bf16(a3, bfr, acc[3], 0, 0, 0);
      }
      const int ncol = n16 * 16 + (l & 15);
      const int rb = (l >> 4) * 4;
#pragma unroll
      for (int mb = 0; mb < 4; ++mb)
#pragma unroll
        for (int r = 0; r < 4; ++r)
          zout[(size_t)(mb * 16 + rb + r) * ZC + ncol] = acc[mb][r];
    }
  } else if (wg < 320) {
    if (t < NT) do_fl2(p, sm, wg - 256, tid);
  } else if (wg < 328) {
    if (t + 1 < NT) do_s1(p, ws + M2_PM1, t + 1, wg - 320, tid);
  }
}

template<bool USEMEM>
__device__ void phase2_2(const Params& p, float* sm, int wg, int tid, int t) {
  float* ws = p.ws;
  unsigned short* u16 = (unsigned short*)(ws + M2_FEND);
  if (wg < 64) {
    if (t < NT) {
      const int b = wg;
      float* h_sh = sm;
      float* q_sh = sm + 1024;
      float* red  = sm + 1152;
      float* w_sh = sm + 1408;
      float* c_a  = ws + M2_CA;
      float* h_a  = ws + M2_HA;
      unsigned short* xA = u16 + M2_X16A + (size_t)b * KA;
      unsigned short* xD = u16 + M2_X16D + (size_t)b * KD;
      const float* za0 = ws + M2_ZAP + (size_t)b * ZC;
      const float* za1 = za0 + (size_t)NB * ZC;
#pragma unroll
      for (int j = 0; j < 4; ++j) {
        const int g = tid + j * 256;
        const float zi = p.ab[g]        + za0[g]        + za1[g];
        const float zf = p.ab[1024 + g] + za0[1024 + g] + za1[1024 + g];
        const float zg = p.ab[2048 + g] + za0[2048 + g] + za1[2048 + g];
        const float zo = p.ab[3072 + g] + za0[3072 + g] + za1[3072 + g];
        const float cold = c_a[b * NA + g];
        const float iv = sigm(zi), fv = sigm(zf), gv = tanh_t(zg), ov = sigm(zo);
        const float c2 = fv * cold + iv * gv;
        const float h2 = ov * tanh_t(c2);
        c_a[b * NA + g] = c2;
        h_a[b * NA + g] = h2;
        h_sh[g] = h2;
        xA[768 + g] = f2bf(h2);
        xD[g]       = f2bf(h2);
      }
      __syncthreads();
      {
        const int ad = tid & 127, kh = tid >> 7;
        float acc = 0.f;
        const float* wqp = p.wq + ad;
#pragma unroll 8
        for (int k = kh * 512; k < kh * 512 + 512; ++k) acc += h_sh[k] * wqp[(size_t)k * NAD];
        red[tid] = acc;
      }
      __syncthreads();
      if (tid < 128) q_sh[tid] = red[tid] + red[tid + 128];
      __syncthreads();
      float ev = 0.f;
      {
        const unsigned short* flp = u16 + M2_FL16 + (size_t)(b * NAD) * NS + tid;
#pragma unroll 8
        for (int ad = 0; ad < NAD; ++ad)
          ev += tanh_t(q_sh[ad] + bf2f(flp[(size_t)ad * NS])) * p.vatt[ad];
      }
      red[tid] = ev; __syncthreads();
      for (int off = 128; off > 0; off >>= 1) {
        if (tid < off) red[tid] = fmaxf(red[tid], red[tid + off]);
        __syncthreads();
      }
      const float mx = red[0];
      __syncthreads();
      const float ex = __expf(ev - mx);
      red[tid] = ex; __syncthreads();
      for (int off = 128; off > 0; off >>= 1) {
        if (tid < off) red[tid] += red[tid + off];
        __syncthreads();
      }
      const float wv = ex / red[0];
      w_sh[tid] = wv;
      ws[M2_WGL + b * NS + tid] = wv;
      ws[M2_WCU + b * NS + tid] += wv;
      p.out[ALIGN_BASE + (size_t)b * NT * NS + (size_t)t * NS + tid] = wv;
      __syncthreads();
      {
        float a0 = 0.f, a1 = 0.f;
        if constexpr (USEMEM) {
          const unsigned short* mb16 = u16 + M2_MEM16 + (size_t)b * NS * NE;
#pragma unroll 8
          for (int ss = 0; ss < NS; ++ss) {
            const float wcur = w_sh[ss];
            a0 += wcur * bf2f(mb16[(size_t)ss * NE + tid]);
            a1 += wcur * bf2f(mb16[(size_t)ss * NE + tid + 256]);
          }
        } else {
          const float* mb = p.memory + (size_t)b * NS * NE;
#pragma unroll 8
          for (int ss = 0; ss < NS; ++ss) {
            const float wcur = w_sh[ss];
            a0 += wcur * mb[(size_t)ss * NE + tid];
            a1 += wcur * mb[(size_t)ss * NE + tid + 256];
          }
        }
        float* cdst = ws + M2_CTX + (t & 1) * (NB * NE) + b * NE;
        cdst[tid] = a0;
        cdst[tid + 256] = a1;
        xA[256 + tid]  = f2bf(a0);
        xA[512 + tid]  = f2bf(a1);
        xD[1024 + tid] = f2bf(a0);
        xD[1280 + tid] = f2bf(a1);
      }
    }
  } else if (wg < 128) {
    if (t >= 1) {
      const int b = wg - 64;
      const int tm1 = t - 1;
      float* h_sh = sm;
      float* red  = sm + 1024;
      float* c_d  = ws + M2_CD;
      float* h_d  = ws + M2_HD;
      unsigned short* xD = u16 + M2_X16D + (size_t)b * KD;
      const float* zd0 = ws + M2_ZDP + (size_t)b * ZC;
      const float* zd1 = zd0 + (size_t)NB * ZC;
#pragma unroll
      for (int j = 0; j < 4; ++j) {
        const int g = tid + j * 256;
        const float zi = p.db[g]        + zd0[g]        + zd1[g];
        const float zf = p.db[1024 + g] + zd0[1024 + g] + zd1[1024 + g];
        const float zg = p.db[2048 + g] + zd0[2048 + g] + zd1[2048 + g];
        const float zo = p.db[3072 + g] + zd0[3072 + g] + zd1[3072 + g];
        const float cold = c_d[b * ND + g];
        const float iv = sigm(zi), fv = sigm(zf), gv = tanh_t(zg), ov = sigm(zo);
        const float c2 = fv * cold + iv * gv;
        const float h2 = ov * tanh_t(c2);
        c_d[b * ND + g] = c2;
        h_d[b * ND + g] = h2;
        h_sh[g] = h2;
        xD[1536 + g] = f2bf(h2);
      }
      __syncthreads();
      const float* ctxp = ws + M2_CTX + (tm1 & 1) * (NB * NE) + b * NE;
      {
        float acc = 0.f;
        for (int k = tid; k < 1536; k += 256) {
          const float v = (k < 1024) ? h_sh[k] : ctxp[k - 1024];
          acc += v * p.gatew[k];
        }
        red[tid] = acc;
      }
      __syncthreads();
      for (int off = 128; off > 0; off >>= 1) {
        if (tid < off) red[tid] += red[tid + off];
        __syncthreads();
      }
      if (tid == 0) p.out[STOP_BASE + (size_t)b * NT + tm1] = sigm(red[0] + p.gateb[0]);
      __syncthreads();
      if (tid < 240) {
        const int m = tid % 80, kh = tid / 80;
        float acc = 0.f;
#pragma unroll 4
        for (int k = kh * 512; k < kh * 512 + 512; ++k) {
          const float v = (k < 1024) ? h_sh[k] : ctxp[k - 1024];
          acc += v * p.projw[(size_t)k * 80 + m];
        }
        red[kh * 80 + m] = acc;
      }
      __syncthreads();
      if (tid < 80) {
        const float mval = p.projb[tid] + red[tid] + red[80 + tid] + red[160 + tid];
        p.out[MEL_BASE + (size_t)b * NT * NMEL + (size_t)tm1 * NMEL + tid] = mval;
      }
    }
  } else if (wg < 144) {
    if (t + 1 < NT)
      do_s2<2>(p, ws + M2_PM1, nullptr, u16 + M2_X16A, wg - 128, tid);
  }
}

template<bool USEMEM>
__global__ __launch_bounds__(256, 2) void taco2(Params p) {
  cg::grid_group grid = cg::this_grid();
  const int wg  = blockIdx.x;
  const int tid = threadIdx.x;
  __shared__ float sm[SMN];

  pre_a2<USEMEM>(p, sm, wg, tid);
  grid.sync();
  if (wg >= 128 && wg < 144)
    do_s2<2>(p, p.ws + M2_PM1, nullptr,
             (unsigned short*)(p.ws + M2_FEND) + M2_X16A, wg - 128, tid);
  grid.sync();
  unsigned* bar = (unsigned*)(p.ws + M2_BAR);
  for (int t = 0; t <= NT; ++t) {
    phase1_2(p, sm, wg, tid, t);
    gbar(bar, wg, tid);
    phase2_2<USEMEM>(p, sm, wg, tid, t);
    gbar(bar, wg, tid);
  }
}

extern "C" void kernel_launch(void* const* d_in, const int* in_sizes, int n_in,
                              void* d_out, int out_size, void* d_ws, size_t ws_size,
                              hipStream_t stream) {
  (void)in_sizes; (void)n_in; (void)out_size;
  Params prm;
  prm.memory = (const float*)d_in[0];
  prm.mel    = (const float*)d_in[1];
  prm.pw1    = (const float*)d_in[2];
  prm.pw2    = (const float*)d_in[3];
  prm.awx    = (const float*)d_in[4];
  prm.awh    = (const float*)d_in[5];
  prm.ab     = (const float*)d_in[6];
  prm.wq     = (const float*)d_in[7];
  prm.wm     = (const float*)d_in[8];
  prm.lconv  = (const float*)d_in[9];
  prm.wloc   = (const float*)d_in[10];
  prm.vatt   = (const float*)d_in[11];
  prm.dwx    = (const float*)d_in[12];
  prm.dwh    = (const float*)d_in[13];
  prm.db     = (const float*)d_in[14];
  prm.projw  = (const float*)d_in[15];
  prm.projb  = (const float*)d_in[16];
  prm.gatew  = (const float*)d_in[17];
  prm.gateb  = (const float*)d_in[18];
  prm.out = (float*)d_out;
  prm.ws  = (float*)d_ws;

  void* args[] = { &prm };
  hipError_t err = hipErrorUnknown;
  if (ws_size >= (size_t)M3_BYTES) {
    (void)hipFuncSetAttribute((const void*)taco3,
                              hipFuncAttributeMaxDynamicSharedMemorySize, DYN_LDS);
    err = hipLaunchCooperativeKernel((void*)taco3, dim3(G3), dim3(T3),
                                     args, DYN_LDS, stream);
  }
  if (err != hipSuccess && ws_size >= (size_t)M2_BYTES)
    err = hipLaunchCooperativeKernel((void*)taco2<true>, dim3(G), dim3(256), args, 0, stream);
  if (err != hipSuccess && ws_size >= (size_t)M2_BYTES_NM)
    err = hipLaunchCooperativeKernel((void*)taco2<false>, dim3(G), dim3(256), args, 0, stream);
}